// Round 7
// baseline (88.328 us; speedup 1.0000x reference)
//
#include <hip/hip_runtime.h>

// SurveyEmbeddings forward:
//   placeholder = (answer<=1) ? answer*lin_w + lin_b : ans_emb[answer]
//   out = LN(placeholder)*ln_g + ln_b + alpha*year_emb[year[b]] + beta*q_emb[q]
//
// out[B=4096, Q=1024, D=16] fp32 (268 MB) — memory-bound, write-dominated.
//
// R2: 2x unroll blew VGPRs -> occupancy halved -> 2x slower.
// R3: no grid-stride loop -> un-hoisted constant loads -> 10% slower.
// R4: grid-stride + launch_bounds(256,8) + int32 + scalar year: 50.8us.
// R5: software pipeline + DPP reduce: 52.5us — not latency-bound.
// R6: grid capped at 2048 blocks (one resident dispatch round): 48.9us. BEST.
// R7: R6 body, ONLY change = plain store instead of nontemporal.
//     Hypothesis: nt hint changes L2 write policy; the 6.9TB/s fill kernel
//     uses plain stores; table L2-pollution was never a real threat (~340KB).

typedef float f32x4 __attribute__((ext_vector_type(4)));

#define LN_EPS 1e-5f

template <bool QPOW2>
__global__ __launch_bounds__(256, 8) void survey_fwd(
    const int* __restrict__ year,
    const int* __restrict__ answer,
    const f32x4* __restrict__ ans_emb,   // [VOCAB][4]
    const f32x4* __restrict__ lin_w,     // [4]
    const f32x4* __restrict__ lin_b,     // [4]
    const f32x4* __restrict__ ln_g,      // [4]
    const f32x4* __restrict__ ln_b,      // [4]
    const f32x4* __restrict__ year_emb,  // [N_YEARS][4]
    const f32x4* __restrict__ q_emb,     // [Q][4]
    const float* __restrict__ alpha,
    const float* __restrict__ beta,
    f32x4* __restrict__ out,             // [B*Q][4]
    int total, int Q, int qShift)
{
    const float A  = alpha[0];
    const float Bc = beta[0];

    const int sub = threadIdx.x & 3;     // float4 slot within the D=16 row
    const f32x4 g  = ln_g[sub];
    const f32x4 bb = ln_b[sub];

    const int stride = (int)(gridDim.x * blockDim.x);
    int i = (int)(blockIdx.x * blockDim.x + threadIdx.x);

    for (; i < total; i += stride) {
        const int row = i >> 2;
        const int a   = answer[row];       // 4 lanes broadcast-read same addr

        // categorical branch: gather 16B of the 64B embedding row (L2-hot)
        f32x4 v = ans_emb[a * 4 + sub];

        // continuous branch — rare (~0.05%); table loads stay inside so
        // lin_w/lin_b don't occupy hot-path VGPRs
        if (a <= 1) {
            const f32x4 w  = lin_w[sub];
            const f32x4 lb = lin_b[sub];
            const float af = (float)a;
            v.x = af * w.x + lb.x;
            v.y = af * w.y + lb.y;
            v.z = af * w.z + lb.z;
            v.w = af * w.w + lb.w;
        }

        // LayerNorm over D=16 across the 4-lane group
        float s = v.x + v.y + v.z + v.w;
        s += __shfl_xor(s, 1);
        s += __shfl_xor(s, 2);
        const float mu = s * 0.0625f;

        const float dx = v.x - mu, dy = v.y - mu, dz = v.z - mu, dw = v.w - mu;
        float ss = dx * dx + dy * dy + dz * dz + dw * dw;
        ss += __shfl_xor(ss, 1);
        ss += __shfl_xor(ss, 2);
        const float r = rsqrtf(ss * 0.0625f + LN_EPS);

        const int b = QPOW2 ? (row >> qShift) : (row / Q);
        const int q = QPOW2 ? (row & (Q - 1)) : (row - b * Q);

        // year index is uniform across the block when Q % 64 == 0
        // (a 256-thread block covers 64 consecutive rows, 64 | Q):
        // readfirstlane -> scalar load path, one less VMEM per iteration.
        int yr;
        if (QPOW2 && qShift >= 6) {
            const int b_u = __builtin_amdgcn_readfirstlane(b);
            yr = year[b_u];
        } else {
            yr = year[b];
        }
        const f32x4 ye = year_emb[yr * 4 + sub];
        const f32x4 qe = q_emb[q * 4 + sub];   // L2-hot 64KB table

        f32x4 o;
        o.x = dx * r * g.x + bb.x + A * ye.x + Bc * qe.x;
        o.y = dy * r * g.y + bb.y + A * ye.y + Bc * qe.y;
        o.z = dz * r * g.z + bb.z + A * ye.z + Bc * qe.z;
        o.w = dw * r * g.w + bb.w + A * ye.w + Bc * qe.w;

        out[i] = o;                      // plain store (A/B vs nontemporal)
    }
}

extern "C" void kernel_launch(void* const* d_in, const int* in_sizes, int n_in,
                              void* d_out, int out_size, void* d_ws, size_t ws_size,
                              hipStream_t stream) {
    const int*   year     = (const int*)d_in[0];
    const int*   answer   = (const int*)d_in[1];
    const f32x4* ans_emb  = (const f32x4*)d_in[2];
    const f32x4* lin_w    = (const f32x4*)d_in[3];
    const f32x4* lin_b    = (const f32x4*)d_in[4];
    const f32x4* ln_g     = (const f32x4*)d_in[5];
    const f32x4* ln_b     = (const f32x4*)d_in[6];
    const f32x4* year_emb = (const f32x4*)d_in[7];
    const f32x4* q_emb    = (const f32x4*)d_in[8];
    const float* alpha    = (const float*)d_in[9];
    const float* beta     = (const float*)d_in[10];
    float*       out      = (float*)d_out;

    const int B     = in_sizes[0];
    const int nrows = in_sizes[1];       // B*Q
    const int Q     = nrows / B;
    const int total = nrows * 4;         // one float4 per lane-task

    int blocks = (total + 255) / 256;
    // 2048 blocks x 256 thr = 8192 waves = exactly 32 waves/CU on 256 CUs:
    // whole grid resident in ONE dispatch round (R6 win: 50.8 -> 48.9us).
    if (blocks > 2048) blocks = 2048;    // 32 iters/thread at full size

    const bool pow2 = (Q & (Q - 1)) == 0;
    int qShift = 0;
    while ((1 << qShift) < Q) ++qShift;

    if (pow2) {
        survey_fwd<true><<<blocks, 256, 0, stream>>>(
            year, answer, ans_emb, lin_w, lin_b, ln_g, ln_b, year_emb, q_emb,
            alpha, beta, (f32x4*)out, total, Q, qShift);
    } else {
        survey_fwd<false><<<blocks, 256, 0, stream>>>(
            year, answer, ans_emb, lin_w, lin_b, ln_g, ln_b, year_emb, q_emb,
            alpha, beta, (f32x4*)out, total, Q, qShift);
    }
}

// Round 8
// 48.998 us; speedup vs baseline: 1.8027x; 1.8027x over previous
//
#include <hip/hip_runtime.h>

// SurveyEmbeddings forward:
//   placeholder = (answer<=1) ? answer*lin_w + lin_b : ans_emb[answer]
//   out = LN(placeholder)*ln_g + ln_b + alpha*year_emb[year[b]] + beta*q_emb[q]
//
// out[B=4096, Q=1024, D=16] fp32 (268 MB) — memory-bound, write-dominated.
//
// Experiment ledger:
// R2: 2x unroll blew VGPRs -> occupancy halved -> 2x slower.
// R3: no grid-stride loop -> un-hoisted constant loads -> 10% slower.
// R4: grid-stride + launch_bounds(256,8) + int32 + scalar year: 50.8us.
// R5: software pipeline + DPP reduce: 52.5us — NOT latency-bound.
// R6: grid capped at 2048 blocks (one resident dispatch round): 48.9us. BEST.
// R7: plain store instead of nontemporal: 88.3us (1.8x WORSE) — nt store is
//     essential: plain stores write-allocate the 268MB stream into L2,
//     thrashing the gather tables on all 8 XCDs. REVERTED.
// R8 = R6 verbatim. 5.85 TB/s effective = 93% of measured mixed-stream
//     ceiling (6.29 TB/s); VALU ~20% busy; occupancy/latency/grid all tuned.

typedef float f32x4 __attribute__((ext_vector_type(4)));

#define LN_EPS 1e-5f

template <bool QPOW2>
__global__ __launch_bounds__(256, 8) void survey_fwd(
    const int* __restrict__ year,
    const int* __restrict__ answer,
    const f32x4* __restrict__ ans_emb,   // [VOCAB][4]
    const f32x4* __restrict__ lin_w,     // [4]
    const f32x4* __restrict__ lin_b,     // [4]
    const f32x4* __restrict__ ln_g,      // [4]
    const f32x4* __restrict__ ln_b,      // [4]
    const f32x4* __restrict__ year_emb,  // [N_YEARS][4]
    const f32x4* __restrict__ q_emb,     // [Q][4]
    const float* __restrict__ alpha,
    const float* __restrict__ beta,
    f32x4* __restrict__ out,             // [B*Q][4]
    int total, int Q, int qShift)
{
    const float A  = alpha[0];
    const float Bc = beta[0];

    const int sub = threadIdx.x & 3;     // float4 slot within the D=16 row
    const f32x4 g  = ln_g[sub];
    const f32x4 bb = ln_b[sub];

    const int stride = (int)(gridDim.x * blockDim.x);
    int i = (int)(blockIdx.x * blockDim.x + threadIdx.x);

    for (; i < total; i += stride) {
        const int row = i >> 2;
        const int a   = answer[row];       // 4 lanes broadcast-read same addr

        // categorical branch: gather 16B of the 64B embedding row (L2-hot)
        f32x4 v = ans_emb[a * 4 + sub];

        // continuous branch — rare (~0.05%); table loads stay inside so
        // lin_w/lin_b don't occupy hot-path VGPRs
        if (a <= 1) {
            const f32x4 w  = lin_w[sub];
            const f32x4 lb = lin_b[sub];
            const float af = (float)a;
            v.x = af * w.x + lb.x;
            v.y = af * w.y + lb.y;
            v.z = af * w.z + lb.z;
            v.w = af * w.w + lb.w;
        }

        // LayerNorm over D=16 across the 4-lane group
        float s = v.x + v.y + v.z + v.w;
        s += __shfl_xor(s, 1);
        s += __shfl_xor(s, 2);
        const float mu = s * 0.0625f;

        const float dx = v.x - mu, dy = v.y - mu, dz = v.z - mu, dw = v.w - mu;
        float ss = dx * dx + dy * dy + dz * dz + dw * dw;
        ss += __shfl_xor(ss, 1);
        ss += __shfl_xor(ss, 2);
        const float r = rsqrtf(ss * 0.0625f + LN_EPS);

        const int b = QPOW2 ? (row >> qShift) : (row / Q);
        const int q = QPOW2 ? (row & (Q - 1)) : (row - b * Q);

        // year index is uniform across the block when Q % 64 == 0
        // (a 256-thread block covers 64 consecutive rows, 64 | Q):
        // readfirstlane -> scalar load path, one less VMEM per iteration.
        int yr;
        if (QPOW2 && qShift >= 6) {
            const int b_u = __builtin_amdgcn_readfirstlane(b);
            yr = year[b_u];
        } else {
            yr = year[b];
        }
        const f32x4 ye = year_emb[yr * 4 + sub];
        const f32x4 qe = q_emb[q * 4 + sub];   // L2-hot 64KB table

        f32x4 o;
        o.x = dx * r * g.x + bb.x + A * ye.x + Bc * qe.x;
        o.y = dy * r * g.y + bb.y + A * ye.y + Bc * qe.y;
        o.z = dz * r * g.z + bb.z + A * ye.z + Bc * qe.z;
        o.w = dw * r * g.w + bb.w + A * ye.w + Bc * qe.w;

        // nontemporal: bypass L2 write-allocate for the 268MB stream.
        // R7 proved this is worth 1.8x (48.9us vs 88.3us with plain stores).
        __builtin_nontemporal_store(o, &out[i]);
    }
}

extern "C" void kernel_launch(void* const* d_in, const int* in_sizes, int n_in,
                              void* d_out, int out_size, void* d_ws, size_t ws_size,
                              hipStream_t stream) {
    const int*   year     = (const int*)d_in[0];
    const int*   answer   = (const int*)d_in[1];
    const f32x4* ans_emb  = (const f32x4*)d_in[2];
    const f32x4* lin_w    = (const f32x4*)d_in[3];
    const f32x4* lin_b    = (const f32x4*)d_in[4];
    const f32x4* ln_g     = (const f32x4*)d_in[5];
    const f32x4* ln_b     = (const f32x4*)d_in[6];
    const f32x4* year_emb = (const f32x4*)d_in[7];
    const f32x4* q_emb    = (const f32x4*)d_in[8];
    const float* alpha    = (const float*)d_in[9];
    const float* beta     = (const float*)d_in[10];
    float*       out      = (float*)d_out;

    const int B     = in_sizes[0];
    const int nrows = in_sizes[1];       // B*Q
    const int Q     = nrows / B;
    const int total = nrows * 4;         // one float4 per lane-task

    int blocks = (total + 255) / 256;
    // 2048 blocks x 256 thr = 8192 waves = exactly 32 waves/CU on 256 CUs:
    // whole grid resident in ONE dispatch round (R6 win: 50.8 -> 48.9us).
    if (blocks > 2048) blocks = 2048;    // 32 iters/thread at full size

    const bool pow2 = (Q & (Q - 1)) == 0;
    int qShift = 0;
    while ((1 << qShift) < Q) ++qShift;

    if (pow2) {
        survey_fwd<true><<<blocks, 256, 0, stream>>>(
            year, answer, ans_emb, lin_w, lin_b, ln_g, ln_b, year_emb, q_emb,
            alpha, beta, (f32x4*)out, total, Q, qShift);
    } else {
        survey_fwd<false><<<blocks, 256, 0, stream>>>(
            year, answer, ans_emb, lin_w, lin_b, ln_g, ln_b, year_emb, q_emb,
            alpha, beta, (f32x4*)out, total, Q, qShift);
    }
}